// Round 22
// baseline (116.192 us; speedup 1.0000x reference)
//
#include <hip/hip_runtime.h>
#include <hip/hip_bf16.h>
#include <hip/hip_fp8.h>
#include <stdint.h>

#define NHEADS 12
#define HS 64
#define NB 8
#define NL 1024
#define ND 768
#define NE 1536
#define INFV 1000000000000.0f

typedef __bf16 bf16x8 __attribute__((ext_vector_type(8)));
typedef float f32x4 __attribute__((ext_vector_type(4)));

typedef __attribute__((address_space(1))) const unsigned int gas_uint;
typedef __attribute__((address_space(3))) unsigned int las_uint;
#define GLOAD_LDS16(g, l) __builtin_amdgcn_global_load_lds((gas_uint*)(g), (las_uint*)(l), 16, 0, 0)

__device__ __forceinline__ unsigned short f2bf(float f) {
  unsigned int u = __builtin_bit_cast(unsigned int, f);
  u += 0x7fffu + ((u >> 16) & 1u);   // round-to-nearest-even
  return (unsigned short)(u >> 16);
}

__device__ __forceinline__ unsigned char f2fp8(float f) {
  __hip_fp8_e4m3 v(f);               // OCP e4m3, RNE-saturate
  return v.__x;
}

__device__ __forceinline__ bf16x8 load_frag(const unsigned short* p) {
  uint4 v = *(const uint4*)p;
  return __builtin_bit_cast(bf16x8, v);
}

// ---- prep: x->fp8 | W transpose->fp8 | rope trig table ----
__global__ __launch_bounds__(256) void k_prep(
    const float* __restrict__ x, const float* __restrict__ W,
    unsigned char* __restrict__ xb8, unsigned char* __restrict__ wt8,
    float* __restrict__ cst) {
  const int blk = blockIdx.x;
  if (blk < 6144) {
    int i = blk * 256 + threadIdx.x;
    float4 v = ((const float4*)x)[i];
    uchar4 o;
    o.x = f2fp8(v.x); o.y = f2fp8(v.y); o.z = f2fp8(v.z); o.w = f2fp8(v.w);
    ((uchar4*)xb8)[i] = o;
  } else if (blk < 6144 + 288) {
    __shared__ float tile[64][65];
    int t = blk - 6144;
    int te = t % 24, td = t / 24;
    int c = threadIdx.x & 63, r4 = threadIdx.x >> 6;
    #pragma unroll
    for (int rr = 0; rr < 16; rr++) {
      int row = rr * 4 + r4;
      tile[row][c] = W[(size_t)(td * 64 + row) * NE + te * 64 + c];
    }
    __syncthreads();
    #pragma unroll
    for (int rr = 0; rr < 16; rr++) {
      int row = rr * 4 + r4;
      wt8[(size_t)(te * 64 + row) * ND + td * 64 + c] = f2fp8(tile[c][row]);
    }
  } else {
    int t = (blk - 6432) * 256 + threadIdx.x;   // 32768 = 1024*32
    int p = t >> 5, i = t & 31;
    float inv = powf(10000.0f, -(float)i / 32.0f);
    float sv, cv;
    sincosf((float)p * inv, &sv, &cv);
    cst[(p * 32 + i) * 2 + 0] = cv;
    cst[(p * 32 + i) * 2 + 1] = sv;
  }
}

// ---- proj fp8 BK=128 (blocks 0..767) | below-diag fills (768..3455) ----
// A (W^T) 16KB + B (x) 16KB per K-step; 6 K-steps (half the barriers of
// BK=64). XOR swizzle: 8 slots/row, phys = sl^(r&7), pre-swizzled source.
__global__ __launch_bounds__(256, 4) void k_proj_fill(
    const unsigned char* __restrict__ xb8,   // [8192][768] fp8
    const unsigned char* __restrict__ wt8,   // [1536][768] fp8 (W^T)
    const float* __restrict__ bias,          // [1536]
    const float* __restrict__ cst,           // [1024][32] float2 (c,s)
    unsigned short* __restrict__ qbuf, unsigned short* __restrict__ kbuf,
    const int* __restrict__ mask, float* __restrict__ out) {
  const int tid = threadIdx.x;

  __shared__ char smem_b[32768];             // A 16K | B 16K (fp8, BK=128)

  if (blockIdx.x >= 768) {
    // ---- fill path: one below-diagonal 128x128 tile (v=0 mask arith) ----
    const int e   = blockIdx.x - 768;        // 0..2687
    const int bh  = e / 28;
    int u = e % 28;
    int tm = 1;
    #pragma unroll
    for (int k = 0; k < 6; k++) if (u >= tm) { u -= tm; tm++; }
    const int tn = u;                        // tn < tm
    const int b  = bh / NHEADS;
    const int* mrow = mask + b * NL;
    const int n0 = tn * 128 + (tid & 31) * 4;
    int4 mc = *(const int4*)&mrow[n0];
    float o0 = ((mc.x ? 0.0f : -INFV) - INFV) * 0.125f;
    float o1 = ((mc.y ? 0.0f : -INFV) - INFV) * 0.125f;
    float o2 = ((mc.z ? 0.0f : -INFV) - INFV) * 0.125f;
    float o3 = ((mc.w ? 0.0f : -INFV) - INFV) * 0.125f;
    const float oz = (-2.0f * INFV) * 0.125f;
    #pragma unroll
    for (int it = 0; it < 16; it++) {
      int m = tm * 128 + it * 8 + (tid >> 5);
      bool mr1 = (mrow[m] != 0);
      f32x4 o;
      o[0] = mr1 ? o0 : oz;
      o[1] = mr1 ? o1 : oz;
      o[2] = mr1 ? o2 : oz;
      o[3] = mr1 ? o3 : oz;
      __builtin_nontemporal_store(o, (f32x4*)(out + ((size_t)bh * NL + m) * NL + n0));
    }
    return;
  }

  // ---- proj path (fp8, BK=128) ----
  const int blk = blockIdx.x;
  const int xcd = blk & 7;
  const int loc = blk >> 3;
  const int h   = loc % 12;
  const int mt  = xcd * 8 + loc / 12;
  const int m0  = mt * 128;
  const int e0  = h * 128;
  const int lane = tid & 63;
  const int w    = tid >> 6;
  const int wm = w >> 1, wn = w & 1;
  const int col_l = lane & 15, rq = lane >> 4;

  // staging: each tile 128 rows x 8 slots(16B) = 1024 chunks, 4/thread
  unsigned int goff[4];
  #pragma unroll
  for (int q = 0; q < 4; q++) {
    int p = q * 256 + tid;
    int r = p >> 3, sl = p & 7;
    goff[q] = r * ND + (sl ^ (r & 7)) * 16;  // fp8 elements, pre-swizzled src
  }
  const unsigned char* gA = wt8 + (size_t)e0 * ND;
  const unsigned char* gB = xb8 + (size_t)m0 * ND;

  // ds_read: row stride 128B; 8B frag s8=(kkh<<2)|rq ->
  // phys = ((s8>>1) ^ (row&7))*16 + (s8&1)*8 ; row&7 == col_l&7
  const int xr = col_l & 7;
  const unsigned int aBase = (unsigned)((wn * 64 + col_l) * 128);
  const unsigned int bBase = (unsigned)(16384 + (wm * 64 + col_l) * 128);

  f32x4 acc[4][4];   // [e-frag][m-frag]
  #pragma unroll
  for (int i = 0; i < 4; i++)
    #pragma unroll
    for (int j = 0; j < 4; j++)
      #pragma unroll
      for (int q = 0; q < 4; q++) acc[i][j][q] = 0.0f;

  #pragma unroll 1
  for (int kk = 0; kk < ND; kk += 128) {
    const unsigned char* sA = gA + kk;
    const unsigned char* sB = gB + kk;
    #pragma unroll
    for (int q = 0; q < 4; q++) GLOAD_LDS16(sA + goff[q], smem_b + (q * 256 + tid) * 16);
    #pragma unroll
    for (int q = 0; q < 4; q++) GLOAD_LDS16(sB + goff[q], smem_b + 16384 + (q * 256 + tid) * 16);
    __syncthreads();
    #pragma unroll
    for (int kkh = 0; kkh < 4; kkh++) {
      const int s8 = (kkh << 2) | rq;
      const unsigned int so = (unsigned)((((s8 >> 1) ^ xr) * 16) + ((s8 & 1) * 8));
      long long af[4], bfr[4];
      #pragma unroll
      for (int f = 0; f < 4; f++) {
        af[f]  = *(const long long*)(smem_b + aBase + f * 2048 + so);
        bfr[f] = *(const long long*)(smem_b + bBase + f * 2048 + so);
      }
      #pragma unroll
      for (int i = 0; i < 4; i++)
        #pragma unroll
        for (int j = 0; j < 4; j++)
          acc[i][j] = __builtin_amdgcn_mfma_f32_16x16x32_fp8_fp8(af[i], bfr[j], acc[i][j], 0, 0, 0);
    }
    __syncthreads();
  }

  // epilogue: bias + rope (in-thread pairs; one 16B trig load per frag)
  unsigned short* obuf = (wn == 1) ? kbuf : qbuf;   // wave-uniform
  #pragma unroll
  for (int j = 0; j < 4; j++) {
    const int m   = m0 + wm * 64 + j * 16 + col_l;
    const int pos = m & (NL - 1);
    const int bb  = m >> 10;
    const float* crow = cst + pos * 64;
    unsigned short* orow = obuf + (((size_t)(bb * NHEADS + h)) * NL + pos) * HS;
    #pragma unroll
    for (int i = 0; i < 4; i++) {
      const int s0 = i * 16 + rq * 4;
      float4 bv = *(const float4*)&bias[e0 + wn * 64 + s0];
      float4 tq = *(const float4*)(crow + s0);
      float v0 = acc[i][j][0] + bv.x;
      float v1 = acc[i][j][1] + bv.y;
      float v2 = acc[i][j][2] + bv.z;
      float v3 = acc[i][j][3] + bv.w;
      ushort4 o;
      o.x = f2bf(v0 * tq.x - v1 * tq.y);
      o.y = f2bf(v1 * tq.x + v0 * tq.y);
      o.z = f2bf(v2 * tq.z - v3 * tq.w);
      o.w = f2bf(v3 * tq.z + v2 * tq.w);
      *(ushort4*)&orow[s0] = o;
    }
  }
}

// ---- logits: upper-triangle (tn >= tm) tiles, per (b,h) Q @ K^T ----
__global__ __launch_bounds__(256) void k_logits(
    const unsigned short* __restrict__ qbuf,
    const unsigned short* __restrict__ kbuf,
    const int* __restrict__ mask,
    float* __restrict__ out) {
  const int f  = blockIdx.x;
  const int r  = f & 7, t = f >> 3;
  const int bh = r + 8 * (t / 36);
  int u = t % 36;
  int tm = 0;
  #pragma unroll
  for (int k = 0; k < 7; k++) if (u >= 8 - tm) { u -= 8 - tm; tm++; }
  const int tn = tm + u;
  const int b  = bh / NHEADS;
  const int tid  = threadIdx.x;
  const int* mrow = mask + b * NL;

  const int lane = tid & 63;
  const int w    = tid >> 6;
  const int wm = w >> 1, wn = w & 1;
  const int m_base = tm * 128 + wm * 64;
  const int n_base = tn * 128 + wn * 64;
  const int col_l = lane & 15, rq = lane >> 4;
  const unsigned short* Q = qbuf + (size_t)bh * (NL * HS);
  const unsigned short* K = kbuf + (size_t)bh * (NL * HS);

  __shared__ float lds[64 * 132];            // +4 float row pad

  f32x4 acc[4][4];   // [n-frag][m-frag]
  #pragma unroll
  for (int i = 0; i < 4; i++)
    #pragma unroll
    for (int j = 0; j < 4; j++)
      #pragma unroll
      for (int q = 0; q < 4; q++) acc[i][j][q] = 0.0f;

  #pragma unroll
  for (int ks = 0; ks < 2; ks++) {
    bf16x8 ak[4], bq[4];
    #pragma unroll
    for (int ff = 0; ff < 4; ff++) {
      ak[ff] = load_frag(K + (size_t)(n_base + ff * 16 + col_l) * HS + ks * 32 + rq * 8);
      bq[ff] = load_frag(Q + (size_t)(m_base + ff * 16 + col_l) * HS + ks * 32 + rq * 8);
    }
    #pragma unroll
    for (int i = 0; i < 4; i++)
      #pragma unroll
      for (int j = 0; j < 4; j++)
        acc[i][j] = __builtin_amdgcn_mfma_f32_16x16x32_bf16(ak[i], bq[j], acc[i][j], 0, 0, 0);
  }

  const bool diag = (tn == tm);
  const int rb_row = tid >> 5;
  const int rb_c4  = (tid & 31) * 4;
  const int n_rb   = tn * 128 + rb_c4;
  int4 mc_rb = *(const int4*)&mrow[n_rb];
  const bool allmc = (mc_rb.x & mc_rb.y & mc_rb.z & mc_rb.w) != 0;

  #pragma unroll
  for (int pass = 0; pass < 2; pass++) {
    if (wm == pass) {
      #pragma unroll
      for (int j = 0; j < 4; j++) {
        const int rl = j * 16 + col_l;
        #pragma unroll
        for (int i = 0; i < 4; i++)
          *(f32x4*)&lds[rl * 132 + wn * 64 + i * 16 + rq * 4] = acc[i][j];
      }
    }
    __syncthreads();
    #pragma unroll
    for (int it = 0; it < 8; it++) {
      const int rl = it * 8 + rb_row;
      const int m  = tm * 128 + pass * 64 + rl;
      f32x4 v = *(const f32x4*)&lds[rl * 132 + rb_c4];
      if (mrow[m] == 0) { v[0] = -INFV; v[1] = -INFV; v[2] = -INFV; v[3] = -INFV; }
      if (!allmc) {
        if (mc_rb.x == 0) v[0] = -INFV;
        if (mc_rb.y == 0) v[1] = -INFV;
        if (mc_rb.z == 0) v[2] = -INFV;
        if (mc_rb.w == 0) v[3] = -INFV;
      }
      if (diag) {
        if (n_rb + 0 < m) v[0] -= INFV;
        if (n_rb + 1 < m) v[1] -= INFV;
        if (n_rb + 2 < m) v[2] -= INFV;
        if (n_rb + 3 < m) v[3] -= INFV;
      }
      v *= 0.125f;
      __builtin_nontemporal_store(v, (f32x4*)(out + ((size_t)bh * NL + m) * NL + n_rb));
    }
    __syncthreads();
  }
}

extern "C" void kernel_launch(void* const* d_in, const int* in_sizes, int n_in,
                              void* d_out, int out_size, void* d_ws, size_t ws_size,
                              hipStream_t stream) {
  const float* x    = (const float*)d_in[0];
  const float* W    = (const float*)d_in[1];
  const float* bias = (const float*)d_in[2];
  const int*   mask = (const int*)d_in[3];
  float* out = (float*)d_out;
  char* ws = (char*)d_ws;

  unsigned char*  xb8 = (unsigned char*)(ws);              //  6,291,456 B
  unsigned char*  wt8 = (unsigned char*)(ws + 6291456);    //  1,179,648 B
  unsigned short* qb  = (unsigned short*)(ws + 7471104);   // 12,582,912 B
  unsigned short* kb  = (unsigned short*)(ws + 20054016);  // 12,582,912 B
  float* cst = (float*)(ws + 32636928);                    //    262,144 B

  k_prep<<<6560, 256, 0, stream>>>(x, W, xb8, wt8, cst);
  k_proj_fill<<<768 + 2688, 256, 0, stream>>>(xb8, wt8, bias, cst, qb, kb, mask, out);
  k_logits<<<3456, 256, 0, stream>>>(qb, kb, mask, out);
}

// Round 23
// 112.883 us; speedup vs baseline: 1.0293x; 1.0293x over previous
//
#include <hip/hip_runtime.h>
#include <hip/hip_bf16.h>
#include <hip/hip_fp8.h>
#include <stdint.h>

#define NHEADS 12
#define HS 64
#define NB 8
#define NL 1024
#define ND 768
#define NE 1536
#define INFV 1000000000000.0f

typedef __bf16 bf16x8 __attribute__((ext_vector_type(8)));
typedef float f32x4 __attribute__((ext_vector_type(4)));

typedef __attribute__((address_space(1))) const unsigned int gas_uint;
typedef __attribute__((address_space(3))) unsigned int las_uint;
#define GLOAD_LDS16(g, l) __builtin_amdgcn_global_load_lds((gas_uint*)(g), (las_uint*)(l), 16, 0, 0)

__device__ __forceinline__ unsigned short f2bf(float f) {
  unsigned int u = __builtin_bit_cast(unsigned int, f);
  u += 0x7fffu + ((u >> 16) & 1u);   // round-to-nearest-even
  return (unsigned short)(u >> 16);
}

__device__ __forceinline__ unsigned char f2fp8(float f) {
  __hip_fp8_e4m3 v(f);               // OCP e4m3, RNE-saturate
  return v.__x;
}

__device__ __forceinline__ bf16x8 load_frag(const unsigned short* p) {
  uint4 v = *(const uint4*)p;
  return __builtin_bit_cast(bf16x8, v);
}

// ---- prep: x->fp8 | W transpose->fp8 | rope trig table ----
__global__ __launch_bounds__(256) void k_prep(
    const float* __restrict__ x, const float* __restrict__ W,
    unsigned char* __restrict__ xb8, unsigned char* __restrict__ wt8,
    float* __restrict__ cst) {
  const int blk = blockIdx.x;
  if (blk < 6144) {
    int i = blk * 256 + threadIdx.x;
    float4 v = ((const float4*)x)[i];
    uchar4 o;
    o.x = f2fp8(v.x); o.y = f2fp8(v.y); o.z = f2fp8(v.z); o.w = f2fp8(v.w);
    ((uchar4*)xb8)[i] = o;
  } else if (blk < 6144 + 288) {
    __shared__ float tile[64][65];
    int t = blk - 6144;
    int te = t % 24, td = t / 24;
    int c = threadIdx.x & 63, r4 = threadIdx.x >> 6;
    #pragma unroll
    for (int rr = 0; rr < 16; rr++) {
      int row = rr * 4 + r4;
      tile[row][c] = W[(size_t)(td * 64 + row) * NE + te * 64 + c];
    }
    __syncthreads();
    #pragma unroll
    for (int rr = 0; rr < 16; rr++) {
      int row = rr * 4 + r4;
      wt8[(size_t)(te * 64 + row) * ND + td * 64 + c] = f2fp8(tile[c][row]);
    }
  } else {
    int t = (blk - 6432) * 256 + threadIdx.x;   // 32768 = 1024*32
    int p = t >> 5, i = t & 31;
    float inv = powf(10000.0f, -(float)i / 32.0f);
    float sv, cv;
    sincosf((float)p * inv, &sv, &cv);
    cst[(p * 32 + i) * 2 + 0] = cv;
    cst[(p * 32 + i) * 2 + 1] = sv;
  }
}

// ---- proj fp8 BK=64 DOUBLE-BUFFERED (0..767) | fills (768..3455) ----
// 2 x 16KB LDS buffers; counted s_waitcnt vmcnt(4) + raw s_barrier: next
// tile's 4 loads stay in flight across the barrier (no vmcnt(0) drain
// in the main loop). Swizzle identical to R21.
__global__ __launch_bounds__(256, 4) void k_proj_fill(
    const unsigned char* __restrict__ xb8,   // [8192][768] fp8
    const unsigned char* __restrict__ wt8,   // [1536][768] fp8 (W^T)
    const float* __restrict__ bias,          // [1536]
    const float* __restrict__ cst,           // [1024][32] float2 (c,s)
    unsigned short* __restrict__ qbuf, unsigned short* __restrict__ kbuf,
    const int* __restrict__ mask, float* __restrict__ out) {
  const int tid = threadIdx.x;

  __shared__ char smem_b[32768];             // buf0: A@0 B@8K | buf1: A@16K B@24K

  if (blockIdx.x >= 768) {
    // ---- fill path: one below-diagonal 128x128 tile (v=0 mask arith) ----
    const int e   = blockIdx.x - 768;        // 0..2687
    const int bh  = e / 28;
    int u = e % 28;
    int tm = 1;
    #pragma unroll
    for (int k = 0; k < 6; k++) if (u >= tm) { u -= tm; tm++; }
    const int tn = u;                        // tn < tm
    const int b  = bh / NHEADS;
    const int* mrow = mask + b * NL;
    const int n0 = tn * 128 + (tid & 31) * 4;
    int4 mc = *(const int4*)&mrow[n0];
    float o0 = ((mc.x ? 0.0f : -INFV) - INFV) * 0.125f;
    float o1 = ((mc.y ? 0.0f : -INFV) - INFV) * 0.125f;
    float o2 = ((mc.z ? 0.0f : -INFV) - INFV) * 0.125f;
    float o3 = ((mc.w ? 0.0f : -INFV) - INFV) * 0.125f;
    const float oz = (-2.0f * INFV) * 0.125f;
    #pragma unroll
    for (int it = 0; it < 16; it++) {
      int m = tm * 128 + it * 8 + (tid >> 5);
      bool mr1 = (mrow[m] != 0);
      f32x4 o;
      o[0] = mr1 ? o0 : oz;
      o[1] = mr1 ? o1 : oz;
      o[2] = mr1 ? o2 : oz;
      o[3] = mr1 ? o3 : oz;
      __builtin_nontemporal_store(o, (f32x4*)(out + ((size_t)bh * NL + m) * NL + n0));
    }
    return;
  }

  // ---- proj path (fp8, BK=64, double-buffered) ----
  const int blk = blockIdx.x;
  const int xcd = blk & 7;
  const int loc = blk >> 3;
  const int h   = loc % 12;
  const int mt  = xcd * 8 + loc / 12;
  const int m0  = mt * 128;
  const int e0  = h * 128;
  const int lane = tid & 63;
  const int w    = tid >> 6;
  const int wm = w >> 1, wn = w & 1;
  const int col_l = lane & 15, rq = lane >> 4;

  // staging: 512 16B chunks per 8KB tile, 2 insts/thread/tile (A and B)
  unsigned int goff[2];
  #pragma unroll
  for (int q = 0; q < 2; q++) {
    int p = q * 256 + tid;
    int r = p >> 2, sl = p & 3;
    goff[q] = r * ND + (sl ^ (r & 3)) * 16;  // fp8 elements, pre-swizzled src
  }
  const unsigned char* gA = wt8 + (size_t)e0 * ND;
  const unsigned char* gB = xb8 + (size_t)m0 * ND;

  const int xr3 = col_l & 3;
  const unsigned int aBase = (unsigned)((wn * 64 + col_l) * 64);
  const unsigned int bBase = (unsigned)(8192 + (wm * 64 + col_l) * 64);

  f32x4 acc[4][4];   // [e-frag][m-frag]
  #pragma unroll
  for (int i = 0; i < 4; i++)
    #pragma unroll
    for (int j = 0; j < 4; j++)
      #pragma unroll
      for (int q = 0; q < 4; q++) acc[i][j][q] = 0.0f;

  // prologue: stage tile 0 into buf0
  #pragma unroll
  for (int q = 0; q < 2; q++) {
    GLOAD_LDS16(gA + goff[q],        smem_b + (q * 256 + tid) * 16);
    GLOAD_LDS16(gB + goff[q], smem_b + 8192 + (q * 256 + tid) * 16);
  }

  #pragma unroll
  for (int t = 0; t < 12; t++) {
    const unsigned int bufo = (unsigned)((t & 1) * 16384);
    if (t < 11) {
      const unsigned int nbufo = (unsigned)(((t + 1) & 1) * 16384);
      const unsigned char* sA = gA + (t + 1) * 64;
      const unsigned char* sB = gB + (t + 1) * 64;
      #pragma unroll
      for (int q = 0; q < 2; q++) {
        GLOAD_LDS16(sA + goff[q], smem_b + nbufo + (q * 256 + tid) * 16);
        GLOAD_LDS16(sB + goff[q], smem_b + nbufo + 8192 + (q * 256 + tid) * 16);
      }
      asm volatile("s_waitcnt vmcnt(4)" ::: "memory");  // tile-t loads done
    } else {
      asm volatile("s_waitcnt vmcnt(0)" ::: "memory");
    }
    __builtin_amdgcn_s_barrier();            // all waves' tile-t loads visible
    #pragma unroll
    for (int kkh = 0; kkh < 2; kkh++) {
      const int s8 = (kkh << 2) | rq;
      const unsigned int so = (unsigned)((((s8 >> 1) ^ xr3) * 16) + ((s8 & 1) * 8));
      long long af[4], bfr[4];
      #pragma unroll
      for (int f = 0; f < 4; f++) {
        af[f]  = *(const long long*)(smem_b + bufo + aBase + f * 1024 + so);
        bfr[f] = *(const long long*)(smem_b + bufo + bBase + f * 1024 + so);
      }
      #pragma unroll
      for (int i = 0; i < 4; i++)
        #pragma unroll
        for (int j = 0; j < 4; j++)
          acc[i][j] = __builtin_amdgcn_mfma_f32_16x16x32_fp8_fp8(af[i], bfr[j], acc[i][j], 0, 0, 0);
    }
    __builtin_amdgcn_s_barrier();            // compute(t) done before buf reuse
  }

  // epilogue: bias + rope (in-thread pairs; one 16B trig load per frag)
  unsigned short* obuf = (wn == 1) ? kbuf : qbuf;   // wave-uniform
  #pragma unroll
  for (int j = 0; j < 4; j++) {
    const int m   = m0 + wm * 64 + j * 16 + col_l;
    const int pos = m & (NL - 1);
    const int bb  = m >> 10;
    const float* crow = cst + pos * 64;
    unsigned short* orow = obuf + (((size_t)(bb * NHEADS + h)) * NL + pos) * HS;
    #pragma unroll
    for (int i = 0; i < 4; i++) {
      const int s0 = i * 16 + rq * 4;
      float4 bv = *(const float4*)&bias[e0 + wn * 64 + s0];
      float4 tq = *(const float4*)(crow + s0);
      float v0 = acc[i][j][0] + bv.x;
      float v1 = acc[i][j][1] + bv.y;
      float v2 = acc[i][j][2] + bv.z;
      float v3 = acc[i][j][3] + bv.w;
      ushort4 o;
      o.x = f2bf(v0 * tq.x - v1 * tq.y);
      o.y = f2bf(v1 * tq.x + v0 * tq.y);
      o.z = f2bf(v2 * tq.z - v3 * tq.w);
      o.w = f2bf(v3 * tq.z + v2 * tq.w);
      *(ushort4*)&orow[s0] = o;
    }
  }
}

// ---- logits: upper-triangle (tn >= tm) tiles, per (b,h) Q @ K^T ----
__global__ __launch_bounds__(256) void k_logits(
    const unsigned short* __restrict__ qbuf,
    const unsigned short* __restrict__ kbuf,
    const int* __restrict__ mask,
    float* __restrict__ out) {
  const int f  = blockIdx.x;
  const int r  = f & 7, t = f >> 3;
  const int bh = r + 8 * (t / 36);
  int u = t % 36;
  int tm = 0;
  #pragma unroll
  for (int k = 0; k < 7; k++) if (u >= 8 - tm) { u -= 8 - tm; tm++; }
  const int tn = tm + u;
  const int b  = bh / NHEADS;
  const int tid  = threadIdx.x;
  const int* mrow = mask + b * NL;

  const int lane = tid & 63;
  const int w    = tid >> 6;
  const int wm = w >> 1, wn = w & 1;
  const int m_base = tm * 128 + wm * 64;
  const int n_base = tn * 128 + wn * 64;
  const int col_l = lane & 15, rq = lane >> 4;
  const unsigned short* Q = qbuf + (size_t)bh * (NL * HS);
  const unsigned short* K = kbuf + (size_t)bh * (NL * HS);

  __shared__ float lds[64 * 132];            // +4 float row pad

  f32x4 acc[4][4];   // [n-frag][m-frag]
  #pragma unroll
  for (int i = 0; i < 4; i++)
    #pragma unroll
    for (int j = 0; j < 4; j++)
      #pragma unroll
      for (int q = 0; q < 4; q++) acc[i][j][q] = 0.0f;

  #pragma unroll
  for (int ks = 0; ks < 2; ks++) {
    bf16x8 ak[4], bq[4];
    #pragma unroll
    for (int ff = 0; ff < 4; ff++) {
      ak[ff] = load_frag(K + (size_t)(n_base + ff * 16 + col_l) * HS + ks * 32 + rq * 8);
      bq[ff] = load_frag(Q + (size_t)(m_base + ff * 16 + col_l) * HS + ks * 32 + rq * 8);
    }
    #pragma unroll
    for (int i = 0; i < 4; i++)
      #pragma unroll
      for (int j = 0; j < 4; j++)
        acc[i][j] = __builtin_amdgcn_mfma_f32_16x16x32_bf16(ak[i], bq[j], acc[i][j], 0, 0, 0);
  }

  const bool diag = (tn == tm);
  const int rb_row = tid >> 5;
  const int rb_c4  = (tid & 31) * 4;
  const int n_rb   = tn * 128 + rb_c4;
  int4 mc_rb = *(const int4*)&mrow[n_rb];
  const bool allmc = (mc_rb.x & mc_rb.y & mc_rb.z & mc_rb.w) != 0;

  #pragma unroll
  for (int pass = 0; pass < 2; pass++) {
    if (wm == pass) {
      #pragma unroll
      for (int j = 0; j < 4; j++) {
        const int rl = j * 16 + col_l;
        #pragma unroll
        for (int i = 0; i < 4; i++)
          *(f32x4*)&lds[rl * 132 + wn * 64 + i * 16 + rq * 4] = acc[i][j];
      }
    }
    __syncthreads();
    #pragma unroll
    for (int it = 0; it < 8; it++) {
      const int rl = it * 8 + rb_row;
      const int m  = tm * 128 + pass * 64 + rl;
      f32x4 v = *(const f32x4*)&lds[rl * 132 + rb_c4];
      if (mrow[m] == 0) { v[0] = -INFV; v[1] = -INFV; v[2] = -INFV; v[3] = -INFV; }
      if (!allmc) {
        if (mc_rb.x == 0) v[0] = -INFV;
        if (mc_rb.y == 0) v[1] = -INFV;
        if (mc_rb.z == 0) v[2] = -INFV;
        if (mc_rb.w == 0) v[3] = -INFV;
      }
      if (diag) {
        if (n_rb + 0 < m) v[0] -= INFV;
        if (n_rb + 1 < m) v[1] -= INFV;
        if (n_rb + 2 < m) v[2] -= INFV;
        if (n_rb + 3 < m) v[3] -= INFV;
      }
      v *= 0.125f;
      __builtin_nontemporal_store(v, (f32x4*)(out + ((size_t)bh * NL + m) * NL + n_rb));
    }
    __syncthreads();
  }
}

extern "C" void kernel_launch(void* const* d_in, const int* in_sizes, int n_in,
                              void* d_out, int out_size, void* d_ws, size_t ws_size,
                              hipStream_t stream) {
  const float* x    = (const float*)d_in[0];
  const float* W    = (const float*)d_in[1];
  const float* bias = (const float*)d_in[2];
  const int*   mask = (const int*)d_in[3];
  float* out = (float*)d_out;
  char* ws = (char*)d_ws;

  unsigned char*  xb8 = (unsigned char*)(ws);              //  6,291,456 B
  unsigned char*  wt8 = (unsigned char*)(ws + 6291456);    //  1,179,648 B
  unsigned short* qb  = (unsigned short*)(ws + 7471104);   // 12,582,912 B
  unsigned short* kb  = (unsigned short*)(ws + 20054016);  // 12,582,912 B
  float* cst = (float*)(ws + 32636928);                    //    262,144 B

  k_prep<<<6560, 256, 0, stream>>>(x, W, xb8, wt8, cst);
  k_proj_fill<<<768 + 2688, 256, 0, stream>>>(xb8, wt8, bias, cst, qb, kb, mask, out);
  k_logits<<<3456, 256, 0, stream>>>(qb, kb, mask, out);
}